// Round 10
// baseline (140.166 us; speedup 1.0000x reference)
//
#include <hip/hip_runtime.h>
#include <hip/hip_bf16.h>

#define B_ 2
#define T_ 2048
#define D_ 512
#define H_ 8
#define DH_ 64
#define NROW 4096
#define NQKV 1536

typedef __bf16 bf16x8 __attribute__((ext_vector_type(8)));
typedef float f32x4 __attribute__((ext_vector_type(4)));

__device__ __forceinline__ unsigned short f2bf(float f) {
  unsigned int u = __float_as_uint(f);
  unsigned int r = (u + 0x7fffu + ((u >> 16) & 1u)) >> 16;
  return (unsigned short)r;
}
__device__ __forceinline__ float bf2f(unsigned short s) {
  return __uint_as_float(((unsigned int)s) << 16);
}

__device__ __forceinline__ void gload_lds16(const void* g, void* l) {
  __builtin_amdgcn_global_load_lds(
      (__attribute__((address_space(1))) void*)(void*)(g),
      (__attribute__((address_space(3))) void*)(l), 16, 0, 0);
}

// ---------------- prep: weight transpose + cast, bias concat ----------------
__global__ __launch_bounds__(256) void prep_kernel(
    const float* __restrict__ Wq, const float* __restrict__ Wk,
    const float* __restrict__ Wv, const float* __restrict__ Wo,
    const float* __restrict__ bq, const float* __restrict__ bk,
    const float* __restrict__ bv,
    unsigned short* __restrict__ Wt,   // [1536][512] bf16, Wt[n][k] = W*[k][n]
    unsigned short* __restrict__ Wot,  // [512][512]  bf16, Wot[d][hk] = Wo[hk][d]
    float* __restrict__ bias_cat)      // [1536]
{
  int idx = blockIdx.x * 256 + threadIdx.x;
  const int total1 = NQKV * D_;        // 786432
  const int total2 = D_ * D_;          // 262144
  if (idx < total1) {
    int n = idx >> 9, k = idx & 511;
    const float* src = (n < 512) ? Wq : ((n < 1024) ? Wk : Wv);
    int nn = n & 511;
    Wt[idx] = f2bf(src[k * 512 + nn]);
  } else if (idx < total1 + total2) {
    int i = idx - total1;
    int n = i >> 9, k = i & 511;
    Wot[i] = f2bf(Wo[k * 512 + n]);
  } else if (idx < total1 + total2 + NQKV) {
    int i = idx - total1 - total2;
    const float* s = (i < 512) ? bq : ((i < 1024) ? bk : bv);
    bias_cat[i] = s[i & 511];
  }
}

// ---------------- LayerNorm -> bf16 h ----------------
__global__ __launch_bounds__(256) void ln_kernel(
    const float* __restrict__ x, const float* __restrict__ gamma,
    const float* __restrict__ beta, unsigned short* __restrict__ h)
{
  const int lane = threadIdx.x & 63;
  const int row = (blockIdx.x << 2) + (threadIdx.x >> 6);
  const float* xr = x + (size_t)row * D_ + lane * 8;
  float4 v0 = *(const float4*)xr;
  float4 v1 = *(const float4*)(xr + 4);
  float xv[8] = {v0.x, v0.y, v0.z, v0.w, v1.x, v1.y, v1.z, v1.w};
  float s = 0.f, ss = 0.f;
  #pragma unroll
  for (int i = 0; i < 8; ++i) { s += xv[i]; ss += xv[i] * xv[i]; }
  #pragma unroll
  for (int off = 32; off > 0; off >>= 1) {
    s  += __shfl_xor(s, off);
    ss += __shfl_xor(ss, off);
  }
  float mu  = s * (1.0f / D_);
  float var = ss * (1.0f / D_) - mu * mu;
  float rs  = rsqrtf(var + 1e-3f);
  const float* gp = gamma + lane * 8;
  const float* bp = beta + lane * 8;
  float4 g0 = *(const float4*)gp;
  float4 g1 = *(const float4*)(gp + 4);
  float4 b0 = *(const float4*)bp;
  float4 b1 = *(const float4*)(bp + 4);
  float gv[8] = {g0.x, g0.y, g0.z, g0.w, g1.x, g1.y, g1.z, g1.w};
  float bv8[8] = {b0.x, b0.y, b0.z, b0.w, b1.x, b1.y, b1.z, b1.w};
  unsigned int pk[4];
  #pragma unroll
  for (int i = 0; i < 4; ++i) {
    unsigned short lo = f2bf((xv[2*i]   - mu) * rs * gv[2*i]   + bv8[2*i]);
    unsigned short hi = f2bf((xv[2*i+1] - mu) * rs * gv[2*i+1] + bv8[2*i+1]);
    pk[i] = (unsigned int)lo | ((unsigned int)hi << 16);
  }
  uint4 out4 = make_uint4(pk[0], pk[1], pk[2], pk[3]);
  *(uint4*)(h + (size_t)row * D_ + lane * 8) = out4;
}

// ---------------- bf16 MFMA GEMM: C[M][N] = A[M][K] * Bt[N][K]^T ----------------
// EPI=1: out bf16, += bias.  EPI=2: out f32, += bias + resid.
template<int EPI>
__global__ __launch_bounds__(256) void gemm_bf16(
    const unsigned short* __restrict__ A,
    const unsigned short* __restrict__ Bt,
    const float* __restrict__ bias,
    const float* __restrict__ resid,
    void* __restrict__ outp,
    int M, int N, int K)
{
  __shared__ unsigned short Asm[128 * 32];
  __shared__ unsigned short Bsm[128 * 32];
  const int tid = threadIdx.x;
  const int lane = tid & 63;
  const int w = tid >> 6;
  const int m0 = blockIdx.y << 7;
  const int n0 = blockIdx.x << 7;
  const int wr = w >> 1, wc = w & 1;

  f32x4 acc[4][4];
  #pragma unroll
  for (int m = 0; m < 4; ++m)
    #pragma unroll
    for (int n = 0; n < 4; ++n) acc[m][n] = f32x4{0.f, 0.f, 0.f, 0.f};

  const int frow = lane & 15;          // fragment row (M for A, N for Bt)
  const int fk = (lane >> 4) << 3;     // k offset, 8-contiguous per lane

  for (int k0 = 0; k0 < K; k0 += 32) {
    #pragma unroll
    for (int q = 0; q < 2; ++q) {
      const int cbase = ((w << 1) + q) << 6;   // wave-uniform chunk base
      const int c = cbase + lane;              // 16B chunk id, 512 per tile
      gload_lds16(A  + (size_t)(m0 + (c >> 2)) * K + k0 + ((c & 3) << 3),
                  (char*)Asm + cbase * 16);
      gload_lds16(Bt + (size_t)(n0 + (c >> 2)) * K + k0 + ((c & 3) << 3),
                  (char*)Bsm + cbase * 16);
    }
    __syncthreads();
    bf16x8 a[4], b[4];
    #pragma unroll
    for (int m = 0; m < 4; ++m)
      a[m] = *(const bf16x8*)&Asm[((wr << 6) + (m << 4) + frow) * 32 + fk];
    #pragma unroll
    for (int n = 0; n < 4; ++n)
      b[n] = *(const bf16x8*)&Bsm[((wc << 6) + (n << 4) + frow) * 32 + fk];
    #pragma unroll
    for (int m = 0; m < 4; ++m)
      #pragma unroll
      for (int n = 0; n < 4; ++n)
        acc[m][n] = __builtin_amdgcn_mfma_f32_16x16x32_bf16(a[m], b[n], acc[m][n], 0, 0, 0);
    __syncthreads();
  }

  const int rbase = m0 + (wr << 6) + ((lane >> 4) << 2);
  const int cbase = n0 + (wc << 6) + (lane & 15);
  #pragma unroll
  for (int m = 0; m < 4; ++m) {
    #pragma unroll
    for (int n = 0; n < 4; ++n) {
      const int cc = cbase + (n << 4);
      const float bs = bias[cc];
      #pragma unroll
      for (int r = 0; r < 4; ++r) {
        const int rr = rbase + (m << 4) + r;
        const float val = acc[m][n][r] + bs;
        if (EPI == 1) {
          ((unsigned short*)outp)[(size_t)rr * N + cc] = f2bf(val);
        } else {
          const size_t o = (size_t)rr * N + cc;
          ((float*)outp)[o] = val + resid[o];
        }
      }
    }
  }
}

// ---------------- windowed attention ----------------
__global__ __launch_bounds__(256) void attn_kernel(
    const unsigned short* __restrict__ qkv,  // [4096][1536] bf16 (q|k|v)
    unsigned short* __restrict__ ctx)        // [4096][512] bf16
{
  __shared__ float qs[64][64];
  __shared__ float ks[80][64];
  __shared__ float vs[80][64];
  __shared__ float ssm[64][12];
  __shared__ float ps[64][12];
  const int tid = threadIdx.x;
  const int bx = blockIdx.x;
  const int chunk = bx & 31;
  const int hh = (bx >> 5) & 7;
  const int bb = bx >> 8;
  const int t0 = chunk << 6;
  const size_t base_bt = (size_t)(bb * T_) * NQKV + hh * 64;

  for (int e = tid; e < 64 * 64; e += 256) {
    int i = e >> 6, d = e & 63;
    qs[i][d] = bf2f(qkv[base_bt + (size_t)(t0 + i) * NQKV + d]);
  }
  for (int e = tid; e < 80 * 64; e += 256) {
    int i = e >> 6, d = e & 63;
    int tt = t0 - 6 + i;
    bool ok = (tt >= 0) && (tt < T_);
    if (ok) {
      size_t idx = base_bt + (size_t)tt * NQKV + d;
      ks[i][d] = bf2f(qkv[idx + 512]);
      vs[i][d] = bf2f(qkv[idx + 1024]);
    } else {
      ks[i][d] = 0.f;
      vs[i][d] = 0.f;
    }
  }
  __syncthreads();

  for (int e = tid; e < 640; e += 256) {
    int tl = e / 10, j = e - tl * 10;
    int tk = t0 + tl - 6 + j;
    float sc = -1e30f;
    if (tk >= 0 && tk < T_) {
      float a = 0.f;
      #pragma unroll
      for (int d = 0; d < 64; ++d) a += qs[tl][d] * ks[tl + j][d];
      sc = a * 0.125f;
    }
    ssm[tl][j] = sc;
  }
  __syncthreads();

  if (tid < 64) {
    float mx = -1e30f;
    #pragma unroll
    for (int j = 0; j < 10; ++j) mx = fmaxf(mx, ssm[tid][j]);
    float sum = 0.f;
    float e10[10];
    #pragma unroll
    for (int j = 0; j < 10; ++j) { e10[j] = __expf(ssm[tid][j] - mx); sum += e10[j]; }
    float inv = 1.0f / sum;
    #pragma unroll
    for (int j = 0; j < 10; ++j) ps[tid][j] = e10[j] * inv;
  }
  __syncthreads();

  for (int e = tid; e < 64 * 64; e += 256) {
    int tl = e >> 6, d = e & 63;
    float a = 0.f;
    #pragma unroll
    for (int j = 0; j < 10; ++j) a += ps[tl][j] * vs[tl + j][d];
    ctx[(size_t)(bb * T_ + t0 + tl) * D_ + hh * 64 + d] = f2bf(a);
  }
}

extern "C" void kernel_launch(void* const* d_in, const int* in_sizes, int n_in,
                              void* d_out, int out_size, void* d_ws, size_t ws_size,
                              hipStream_t stream) {
  const float* x     = (const float*)d_in[0];
  const float* gamma = (const float*)d_in[1];
  const float* beta  = (const float*)d_in[2];
  const float* Wq    = (const float*)d_in[3];
  const float* bq    = (const float*)d_in[4];
  const float* Wk    = (const float*)d_in[5];
  const float* bk    = (const float*)d_in[6];
  const float* Wv    = (const float*)d_in[7];
  const float* bv    = (const float*)d_in[8];
  const float* Wo    = (const float*)d_in[9];
  const float* bo    = (const float*)d_in[10];
  float* out = (float*)d_out;

  char* ws = (char*)d_ws;
  unsigned short* h   = (unsigned short*)(ws);                        // 4 MB
  unsigned short* Wt  = (unsigned short*)(ws + 4194304);              // 1.5 MB
  unsigned short* Wot = (unsigned short*)(ws + 5767168);              // 0.5 MB
  float* bias_cat     = (float*)(ws + 6291456);                       // 6 KB
  unsigned short* qkv = (unsigned short*)(ws + 6297600);              // 12 MB
  unsigned short* ctx = (unsigned short*)(ws + 6297600 + 12582912);   // 4 MB

  prep_kernel<<<4102, 256, 0, stream>>>(Wq, Wk, Wv, Wo, bq, bk, bv, Wt, Wot, bias_cat);
  ln_kernel<<<1024, 256, 0, stream>>>(x, gamma, beta, h);
  gemm_bf16<1><<<dim3(12, 32), 256, 0, stream>>>(h, Wt, bias_cat, nullptr, qkv, NROW, NQKV, D_);
  attn_kernel<<<512, 256, 0, stream>>>(qkv, ctx);
  gemm_bf16<2><<<dim3(4, 32), 256, 0, stream>>>(ctx, Wot, bo, x, out, NROW, D_, D_);
}

// Round 11
// 136.462 us; speedup vs baseline: 1.0271x; 1.0271x over previous
//
#include <hip/hip_runtime.h>
#include <hip/hip_bf16.h>

#define B_ 2
#define T_ 2048
#define D_ 512
#define H_ 8
#define DH_ 64
#define NROW 4096
#define NQKV 1536

typedef __bf16 bf16x8 __attribute__((ext_vector_type(8)));
typedef float f32x4 __attribute__((ext_vector_type(4)));

__device__ __forceinline__ unsigned short f2bf(float f) {
  unsigned int u = __float_as_uint(f);
  unsigned int r = (u + 0x7fffu + ((u >> 16) & 1u)) >> 16;
  return (unsigned short)r;
}
__device__ __forceinline__ float bf2f(unsigned short s) {
  return __uint_as_float(((unsigned int)s) << 16);
}

__device__ __forceinline__ void gload_lds16(const void* g, void* l) {
  __builtin_amdgcn_global_load_lds(
      (__attribute__((address_space(1))) void*)(void*)(g),
      (__attribute__((address_space(3))) void*)(l), 16, 0, 0);
}

// ---------------- prep: weight transpose + cast, bias concat ----------------
__global__ __launch_bounds__(256) void prep_kernel(
    const float* __restrict__ Wq, const float* __restrict__ Wk,
    const float* __restrict__ Wv, const float* __restrict__ Wo,
    const float* __restrict__ bq, const float* __restrict__ bk,
    const float* __restrict__ bv,
    unsigned short* __restrict__ Wt,   // [1536][512] bf16, Wt[n][k] = W*[k][n]
    unsigned short* __restrict__ Wot,  // [512][512]  bf16, Wot[d][hk] = Wo[hk][d]
    float* __restrict__ bias_cat)      // [1536]
{
  int idx = blockIdx.x * 256 + threadIdx.x;
  const int total1 = NQKV * D_;        // 786432
  const int total2 = D_ * D_;          // 262144
  if (idx < total1) {
    int n = idx >> 9, k = idx & 511;
    const float* src = (n < 512) ? Wq : ((n < 1024) ? Wk : Wv);
    int nn = n & 511;
    Wt[idx] = f2bf(src[k * 512 + nn]);
  } else if (idx < total1 + total2) {
    int i = idx - total1;
    int n = i >> 9, k = i & 511;
    Wot[i] = f2bf(Wo[k * 512 + n]);
  } else if (idx < total1 + total2 + NQKV) {
    int i = idx - total1 - total2;
    const float* s = (i < 512) ? bq : ((i < 1024) ? bk : bv);
    bias_cat[i] = s[i & 511];
  }
}

// ---------------- LayerNorm -> bf16 h ----------------
__global__ __launch_bounds__(256) void ln_kernel(
    const float* __restrict__ x, const float* __restrict__ gamma,
    const float* __restrict__ beta, unsigned short* __restrict__ h)
{
  const int lane = threadIdx.x & 63;
  const int row = (blockIdx.x << 2) + (threadIdx.x >> 6);
  const float* xr = x + (size_t)row * D_ + lane * 8;
  float4 v0 = *(const float4*)xr;
  float4 v1 = *(const float4*)(xr + 4);
  float xv[8] = {v0.x, v0.y, v0.z, v0.w, v1.x, v1.y, v1.z, v1.w};
  float s = 0.f, ss = 0.f;
  #pragma unroll
  for (int i = 0; i < 8; ++i) { s += xv[i]; ss += xv[i] * xv[i]; }
  #pragma unroll
  for (int off = 32; off > 0; off >>= 1) {
    s  += __shfl_xor(s, off);
    ss += __shfl_xor(ss, off);
  }
  float mu  = s * (1.0f / D_);
  float var = ss * (1.0f / D_) - mu * mu;
  float rs  = rsqrtf(var + 1e-3f);
  const float* gp = gamma + lane * 8;
  const float* bp = beta + lane * 8;
  float4 g0 = *(const float4*)gp;
  float4 g1 = *(const float4*)(gp + 4);
  float4 b0 = *(const float4*)bp;
  float4 b1 = *(const float4*)(bp + 4);
  float gv[8] = {g0.x, g0.y, g0.z, g0.w, g1.x, g1.y, g1.z, g1.w};
  float bv8[8] = {b0.x, b0.y, b0.z, b0.w, b1.x, b1.y, b1.z, b1.w};
  unsigned int pk[4];
  #pragma unroll
  for (int i = 0; i < 4; ++i) {
    unsigned short lo = f2bf((xv[2*i]   - mu) * rs * gv[2*i]   + bv8[2*i]);
    unsigned short hi = f2bf((xv[2*i+1] - mu) * rs * gv[2*i+1] + bv8[2*i+1]);
    pk[i] = (unsigned int)lo | ((unsigned int)hi << 16);
  }
  uint4 out4 = make_uint4(pk[0], pk[1], pk[2], pk[3]);
  *(uint4*)(h + (size_t)row * D_ + lane * 8) = out4;
}

// ---------------- bf16 MFMA GEMM: C[M][N] = A[M][K] * Bt[N][K]^T ----------------
// Double-buffered LDS: STAGE(t+1) issued BEFORE compute(t); single barrier/step
// drains prefetch (compiler emits vmcnt(0) lgkmcnt(0) before s_barrier) so the
// global-load latency hides under the 16-MFMA compute phase (T3-minimal, m248).
// EPI=1: out bf16, += bias.  EPI=2: out f32, += bias + resid.
template<int EPI>
__global__ __launch_bounds__(256) void gemm_bf16(
    const unsigned short* __restrict__ A,
    const unsigned short* __restrict__ Bt,
    const float* __restrict__ bias,
    const float* __restrict__ resid,
    void* __restrict__ outp,
    int M, int N, int K)
{
  __shared__ unsigned short Asm[2][128 * 32];
  __shared__ unsigned short Bsm[2][128 * 32];
  const int tid = threadIdx.x;
  const int lane = tid & 63;
  const int w = tid >> 6;
  const int m0 = blockIdx.y << 7;
  const int n0 = blockIdx.x << 7;
  const int wr = w >> 1, wc = w & 1;

  f32x4 acc[4][4];
  #pragma unroll
  for (int m = 0; m < 4; ++m)
    #pragma unroll
    for (int n = 0; n < 4; ++n) acc[m][n] = f32x4{0.f, 0.f, 0.f, 0.f};

  const int frow = lane & 15;          // fragment row (M for A, N for Bt)
  const int fk = (lane >> 4) << 3;     // k offset, 8-contiguous per lane

  const int cbase0 = (w << 1) << 6;    // wave-uniform chunk bases
  const int cbase1 = ((w << 1) + 1) << 6;
  const int c0 = cbase0 + lane;        // 16B chunk ids, 512 per tile
  const int c1 = cbase1 + lane;

  #define STAGE(k0, buf)                                                     \
    do {                                                                     \
      gload_lds16(A  + (size_t)(m0 + (c0 >> 2)) * K + (k0) + ((c0 & 3) << 3),\
                  (char*)Asm[buf] + cbase0 * 16);                            \
      gload_lds16(Bt + (size_t)(n0 + (c0 >> 2)) * K + (k0) + ((c0 & 3) << 3),\
                  (char*)Bsm[buf] + cbase0 * 16);                            \
      gload_lds16(A  + (size_t)(m0 + (c1 >> 2)) * K + (k0) + ((c1 & 3) << 3),\
                  (char*)Asm[buf] + cbase1 * 16);                            \
      gload_lds16(Bt + (size_t)(n0 + (c1 >> 2)) * K + (k0) + ((c1 & 3) << 3),\
                  (char*)Bsm[buf] + cbase1 * 16);                            \
    } while (0)

  STAGE(0, 0);
  __syncthreads();

  const int NT = K >> 5;
  for (int t = 0; t < NT; ++t) {
    const int cur = t & 1;
    if (t + 1 < NT) STAGE((t + 1) << 5, cur ^ 1);
    bf16x8 a[4], b[4];
    #pragma unroll
    for (int m = 0; m < 4; ++m)
      a[m] = *(const bf16x8*)&Asm[cur][((wr << 6) + (m << 4) + frow) * 32 + fk];
    #pragma unroll
    for (int n = 0; n < 4; ++n)
      b[n] = *(const bf16x8*)&Bsm[cur][((wc << 6) + (n << 4) + frow) * 32 + fk];
    #pragma unroll
    for (int m = 0; m < 4; ++m)
      #pragma unroll
      for (int n = 0; n < 4; ++n)
        acc[m][n] = __builtin_amdgcn_mfma_f32_16x16x32_bf16(a[m], b[n], acc[m][n], 0, 0, 0);
    __syncthreads();
  }
  #undef STAGE

  const int rbase = m0 + (wr << 6) + ((lane >> 4) << 2);
  const int cbase = n0 + (wc << 6) + (lane & 15);
  #pragma unroll
  for (int m = 0; m < 4; ++m) {
    #pragma unroll
    for (int n = 0; n < 4; ++n) {
      const int cc = cbase + (n << 4);
      const float bs = bias[cc];
      #pragma unroll
      for (int r = 0; r < 4; ++r) {
        const int rr = rbase + (m << 4) + r;
        const float val = acc[m][n][r] + bs;
        if (EPI == 1) {
          ((unsigned short*)outp)[(size_t)rr * N + cc] = f2bf(val);
        } else {
          const size_t o = (size_t)rr * N + cc;
          ((float*)outp)[o] = val + resid[o];
        }
      }
    }
  }
}

// ---------------- windowed attention ----------------
__global__ __launch_bounds__(256) void attn_kernel(
    const unsigned short* __restrict__ qkv,  // [4096][1536] bf16 (q|k|v)
    unsigned short* __restrict__ ctx)        // [4096][512] bf16
{
  __shared__ float qs[64][64];
  __shared__ float ks[80][64];
  __shared__ float vs[80][64];
  __shared__ float ssm[64][12];
  __shared__ float ps[64][12];
  const int tid = threadIdx.x;
  const int bx = blockIdx.x;
  const int chunk = bx & 31;
  const int hh = (bx >> 5) & 7;
  const int bb = bx >> 8;
  const int t0 = chunk << 6;
  const size_t base_bt = (size_t)(bb * T_) * NQKV + hh * 64;

  for (int e = tid; e < 64 * 64; e += 256) {
    int i = e >> 6, d = e & 63;
    qs[i][d] = bf2f(qkv[base_bt + (size_t)(t0 + i) * NQKV + d]);
  }
  for (int e = tid; e < 80 * 64; e += 256) {
    int i = e >> 6, d = e & 63;
    int tt = t0 - 6 + i;
    bool ok = (tt >= 0) && (tt < T_);
    if (ok) {
      size_t idx = base_bt + (size_t)tt * NQKV + d;
      ks[i][d] = bf2f(qkv[idx + 512]);
      vs[i][d] = bf2f(qkv[idx + 1024]);
    } else {
      ks[i][d] = 0.f;
      vs[i][d] = 0.f;
    }
  }
  __syncthreads();

  for (int e = tid; e < 640; e += 256) {
    int tl = e / 10, j = e - tl * 10;
    int tk = t0 + tl - 6 + j;
    float sc = -1e30f;
    if (tk >= 0 && tk < T_) {
      float a = 0.f;
      #pragma unroll
      for (int d = 0; d < 64; ++d) a += qs[tl][d] * ks[tl + j][d];
      sc = a * 0.125f;
    }
    ssm[tl][j] = sc;
  }
  __syncthreads();

  if (tid < 64) {
    float mx = -1e30f;
    #pragma unroll
    for (int j = 0; j < 10; ++j) mx = fmaxf(mx, ssm[tid][j]);
    float sum = 0.f;
    float e10[10];
    #pragma unroll
    for (int j = 0; j < 10; ++j) { e10[j] = __expf(ssm[tid][j] - mx); sum += e10[j]; }
    float inv = 1.0f / sum;
    #pragma unroll
    for (int j = 0; j < 10; ++j) ps[tid][j] = e10[j] * inv;
  }
  __syncthreads();

  for (int e = tid; e < 64 * 64; e += 256) {
    int tl = e >> 6, d = e & 63;
    float a = 0.f;
    #pragma unroll
    for (int j = 0; j < 10; ++j) a += ps[tl][j] * vs[tl + j][d];
    ctx[(size_t)(bb * T_ + t0 + tl) * D_ + hh * 64 + d] = f2bf(a);
  }
}

extern "C" void kernel_launch(void* const* d_in, const int* in_sizes, int n_in,
                              void* d_out, int out_size, void* d_ws, size_t ws_size,
                              hipStream_t stream) {
  const float* x     = (const float*)d_in[0];
  const float* gamma = (const float*)d_in[1];
  const float* beta  = (const float*)d_in[2];
  const float* Wq    = (const float*)d_in[3];
  const float* bq    = (const float*)d_in[4];
  const float* Wk    = (const float*)d_in[5];
  const float* bk    = (const float*)d_in[6];
  const float* Wv    = (const float*)d_in[7];
  const float* bv    = (const float*)d_in[8];
  const float* Wo    = (const float*)d_in[9];
  const float* bo    = (const float*)d_in[10];
  float* out = (float*)d_out;

  char* ws = (char*)d_ws;
  unsigned short* h   = (unsigned short*)(ws);                        // 4 MB
  unsigned short* Wt  = (unsigned short*)(ws + 4194304);              // 1.5 MB
  unsigned short* Wot = (unsigned short*)(ws + 5767168);              // 0.5 MB
  float* bias_cat     = (float*)(ws + 6291456);                       // 6 KB
  unsigned short* qkv = (unsigned short*)(ws + 6297600);              // 12 MB
  unsigned short* ctx = (unsigned short*)(ws + 6297600 + 12582912);   // 4 MB

  prep_kernel<<<4102, 256, 0, stream>>>(Wq, Wk, Wv, Wo, bq, bk, bv, Wt, Wot, bias_cat);
  ln_kernel<<<1024, 256, 0, stream>>>(x, gamma, beta, h);
  gemm_bf16<1><<<dim3(12, 32), 256, 0, stream>>>(h, Wt, bias_cat, nullptr, qkv, NROW, NQKV, D_);
  attn_kernel<<<512, 256, 0, stream>>>(qkv, ctx);
  gemm_bf16<2><<<dim3(4, 32), 256, 0, stream>>>(ctx, Wot, bo, x, out, NROW, D_, D_);
}

// Round 14
// 129.937 us; speedup vs baseline: 1.0787x; 1.0502x over previous
//
#include <hip/hip_runtime.h>
#include <hip/hip_bf16.h>

#define B_ 2
#define T_ 2048
#define D_ 512
#define H_ 8
#define DH_ 64
#define NROW 4096
#define NQKV 1536

typedef __bf16 bf16x8 __attribute__((ext_vector_type(8)));
typedef float f32x4 __attribute__((ext_vector_type(4)));

__device__ __forceinline__ unsigned short f2bf(float f) {
  unsigned int u = __float_as_uint(f);
  unsigned int r = (u + 0x7fffu + ((u >> 16) & 1u)) >> 16;
  return (unsigned short)r;
}
__device__ __forceinline__ float bf2f(unsigned short s) {
  return __uint_as_float(((unsigned int)s) << 16);
}

__device__ __forceinline__ void gload_lds16(const void* g, void* l) {
  __builtin_amdgcn_global_load_lds(
      (__attribute__((address_space(1))) void*)(void*)(g),
      (__attribute__((address_space(3))) void*)(l), 16, 0, 0);
}

// ---- prep: coalesced 64x64 LDS-tile transpose f32->bf16, + bias concat ----
// blocks 0..255: tile transposes (64 tiles per matrix x {Wq,Wk,Wv,Wo}).
// block 256: bias concat. Reads AND writes coalesced (128B/wave half).
__global__ __launch_bounds__(256) void prep_kernel(
    const float* __restrict__ Wq, const float* __restrict__ Wk,
    const float* __restrict__ Wv, const float* __restrict__ Wo,
    const float* __restrict__ bq, const float* __restrict__ bk,
    const float* __restrict__ bv,
    unsigned short* __restrict__ Wt,   // [1536][512] bf16, Wt[n][k] = W*[k][n]
    unsigned short* __restrict__ Wot,  // [512][512]  bf16, Wot[d][hk] = Wo[hk][d]
    float* __restrict__ bias_cat)      // [1536]
{
  const int bid = blockIdx.x;
  const int tid = threadIdx.x;
  if (bid == 256) {  // bias concat
    for (int i = tid; i < NQKV; i += 256) {
      const float* s = (i < 512) ? bq : ((i < 1024) ? bk : bv);
      bias_cat[i] = s[i & 511];
    }
    return;
  }
  __shared__ unsigned short tile[64][66];  // pad 66: conflict-free col reads
  const int mat = bid >> 6;                // 0..3 = q,k,v,o
  const int tb = bid & 63;
  const int tn = tb >> 3, tk = tb & 7;     // 8x8 tiles of 64x64 over [512][512]
  const int k0 = tk << 6, n0 = tn << 6;
  const float* src = (mat == 0) ? Wq : (mat == 1) ? Wk : (mat == 2) ? Wv : Wo;
  unsigned short* dst = (mat < 3) ? (Wt + (size_t)mat * 512 * 512) : Wot;

  #pragma unroll
  for (int p = 0; p < 16; ++p) {           // load: in[k0+kr][n0+nc], nc fast
    int e = (p << 8) + tid;
    int kr = e >> 6, nc = e & 63;
    tile[kr][nc] = f2bf(src[(size_t)(k0 + kr) * 512 + n0 + nc]);
  }
  __syncthreads();
  #pragma unroll
  for (int p = 0; p < 16; ++p) {           // store: out[n0+nr][k0+kc], kc fast
    int e = (p << 8) + tid;
    int nr = e >> 6, kc = e & 63;
    dst[(size_t)(n0 + nr) * 512 + k0 + kc] = tile[kc][nr];
  }
}

// ---------------- LayerNorm -> bf16 h ----------------
__global__ __launch_bounds__(256) void ln_kernel(
    const float* __restrict__ x, const float* __restrict__ gamma,
    const float* __restrict__ beta, unsigned short* __restrict__ h)
{
  const int lane = threadIdx.x & 63;
  const int row = (blockIdx.x << 2) + (threadIdx.x >> 6);
  const float* xr = x + (size_t)row * D_ + lane * 8;
  float4 v0 = *(const float4*)xr;
  float4 v1 = *(const float4*)(xr + 4);
  float xv[8] = {v0.x, v0.y, v0.z, v0.w, v1.x, v1.y, v1.z, v1.w};
  float s = 0.f, ss = 0.f;
  #pragma unroll
  for (int i = 0; i < 8; ++i) { s += xv[i]; ss += xv[i] * xv[i]; }
  #pragma unroll
  for (int off = 32; off > 0; off >>= 1) {
    s  += __shfl_xor(s, off);
    ss += __shfl_xor(ss, off);
  }
  float mu  = s * (1.0f / D_);
  float var = ss * (1.0f / D_) - mu * mu;
  float rs  = rsqrtf(var + 1e-3f);
  const float* gp = gamma + lane * 8;
  const float* bp = beta + lane * 8;
  float4 g0 = *(const float4*)gp;
  float4 g1 = *(const float4*)(gp + 4);
  float4 b0 = *(const float4*)bp;
  float4 b1 = *(const float4*)(bp + 4);
  float gv[8] = {g0.x, g0.y, g0.z, g0.w, g1.x, g1.y, g1.z, g1.w};
  float bv8[8] = {b0.x, b0.y, b0.z, b0.w, b1.x, b1.y, b1.z, b1.w};
  unsigned int pk[4];
  #pragma unroll
  for (int i = 0; i < 4; ++i) {
    unsigned short lo = f2bf((xv[2*i]   - mu) * rs * gv[2*i]   + bv8[2*i]);
    unsigned short hi = f2bf((xv[2*i+1] - mu) * rs * gv[2*i+1] + bv8[2*i+1]);
    pk[i] = (unsigned int)lo | ((unsigned int)hi << 16);
  }
  uint4 out4 = make_uint4(pk[0], pk[1], pk[2], pk[3]);
  *(uint4*)(h + (size_t)row * D_ + lane * 8) = out4;
}

// ---------------- bf16 MFMA GEMM: C[M][N] = A[M][K] * Bt[N][K]^T ----------------
// Double-buffered LDS: STAGE(t+1) issued BEFORE compute(t).
// EPI=1: out bf16, += bias.  EPI=2: out f32, += bias + resid.
template<int EPI>
__global__ __launch_bounds__(256) void gemm_bf16(
    const unsigned short* __restrict__ A,
    const unsigned short* __restrict__ Bt,
    const float* __restrict__ bias,
    const float* __restrict__ resid,
    void* __restrict__ outp,
    int M, int N, int K)
{
  __shared__ unsigned short Asm[2][128 * 32];
  __shared__ unsigned short Bsm[2][128 * 32];
  const int tid = threadIdx.x;
  const int lane = tid & 63;
  const int w = tid >> 6;
  const int m0 = blockIdx.y << 7;
  const int n0 = blockIdx.x << 7;
  const int wr = w >> 1, wc = w & 1;

  f32x4 acc[4][4];
  #pragma unroll
  for (int m = 0; m < 4; ++m)
    #pragma unroll
    for (int n = 0; n < 4; ++n) acc[m][n] = f32x4{0.f, 0.f, 0.f, 0.f};

  const int frow = lane & 15;          // fragment row (M for A, N for Bt)
  const int fk = (lane >> 4) << 3;     // k offset, 8-contiguous per lane

  const int cbase0 = (w << 1) << 6;    // wave-uniform chunk bases
  const int cbase1 = ((w << 1) + 1) << 6;
  const int c0 = cbase0 + lane;        // 16B chunk ids, 512 per tile
  const int c1 = cbase1 + lane;

  #define STAGE(k0, buf)                                                     \
    do {                                                                     \
      gload_lds16(A  + (size_t)(m0 + (c0 >> 2)) * K + (k0) + ((c0 & 3) << 3),\
                  (char*)Asm[buf] + cbase0 * 16);                            \
      gload_lds16(Bt + (size_t)(n0 + (c0 >> 2)) * K + (k0) + ((c0 & 3) << 3),\
                  (char*)Bsm[buf] + cbase0 * 16);                            \
      gload_lds16(A  + (size_t)(m0 + (c1 >> 2)) * K + (k0) + ((c1 & 3) << 3),\
                  (char*)Asm[buf] + cbase1 * 16);                            \
      gload_lds16(Bt + (size_t)(n0 + (c1 >> 2)) * K + (k0) + ((c1 & 3) << 3),\
                  (char*)Bsm[buf] + cbase1 * 16);                            \
    } while (0)

  STAGE(0, 0);
  __syncthreads();

  const int NT = K >> 5;
  for (int t = 0; t < NT; ++t) {
    const int cur = t & 1;
    if (t + 1 < NT) STAGE((t + 1) << 5, cur ^ 1);
    bf16x8 a[4], b[4];
    #pragma unroll
    for (int m = 0; m < 4; ++m)
      a[m] = *(const bf16x8*)&Asm[cur][((wr << 6) + (m << 4) + frow) * 32 + fk];
    #pragma unroll
    for (int n = 0; n < 4; ++n)
      b[n] = *(const bf16x8*)&Bsm[cur][((wc << 6) + (n << 4) + frow) * 32 + fk];
    #pragma unroll
    for (int m = 0; m < 4; ++m)
      #pragma unroll
      for (int n = 0; n < 4; ++n)
        acc[m][n] = __builtin_amdgcn_mfma_f32_16x16x32_bf16(a[m], b[n], acc[m][n], 0, 0, 0);
    __syncthreads();
  }
  #undef STAGE

  const int rbase = m0 + (wr << 6) + ((lane >> 4) << 2);
  const int cbase = n0 + (wc << 6) + (lane & 15);
  #pragma unroll
  for (int m = 0; m < 4; ++m) {
    #pragma unroll
    for (int n = 0; n < 4; ++n) {
      const int cc = cbase + (n << 4);
      const float bs = bias[cc];
      #pragma unroll
      for (int r = 0; r < 4; ++r) {
        const int rr = rbase + (m << 4) + r;
        const float val = acc[m][n][r] + bs;
        if (EPI == 1) {
          ((unsigned short*)outp)[(size_t)rr * N + cc] = f2bf(val);
        } else {
          const size_t o = (size_t)rr * N + cc;
          ((float*)outp)[o] = val + resid[o];
        }
      }
    }
  }
}

// ---------------- windowed attention ----------------
// qs/ks padded to 65 floats/row: scores-phase reads are same-d/different-row,
// stride-64 rows put all lanes on one bank (G4); +1 pad -> bank=(row+d)%32.
__global__ __launch_bounds__(256) void attn_kernel(
    const unsigned short* __restrict__ qkv,  // [4096][1536] bf16 (q|k|v)
    unsigned short* __restrict__ ctx)        // [4096][512] bf16
{
  __shared__ float qs[64][65];
  __shared__ float ks[80][65];
  __shared__ float vs[80][64];
  __shared__ float ssm[64][12];
  __shared__ float ps[64][12];
  const int tid = threadIdx.x;
  const int bx = blockIdx.x;
  const int chunk = bx & 31;
  const int hh = (bx >> 5) & 7;
  const int bb = bx >> 8;
  const int t0 = chunk << 6;
  const size_t base_bt = (size_t)(bb * T_) * NQKV + hh * 64;

  for (int e = tid; e < 64 * 64; e += 256) {
    int i = e >> 6, d = e & 63;
    qs[i][d] = bf2f(qkv[base_bt + (size_t)(t0 + i) * NQKV + d]);
  }
  for (int e = tid; e < 80 * 64; e += 256) {
    int i = e >> 6, d = e & 63;
    int tt = t0 - 6 + i;
    bool ok = (tt >= 0) && (tt < T_);
    if (ok) {
      size_t idx = base_bt + (size_t)tt * NQKV + d;
      ks[i][d] = bf2f(qkv[idx + 512]);
      vs[i][d] = bf2f(qkv[idx + 1024]);
    } else {
      ks[i][d] = 0.f;
      vs[i][d] = 0.f;
    }
  }
  __syncthreads();

  for (int e = tid; e < 640; e += 256) {
    int tl = e / 10, j = e - tl * 10;
    int tk = t0 + tl - 6 + j;
    float sc = -1e30f;
    if (tk >= 0 && tk < T_) {
      float a = 0.f;
      #pragma unroll
      for (int d = 0; d < 64; ++d) a += qs[tl][d] * ks[tl + j][d];
      sc = a * 0.125f;
    }
    ssm[tl][j] = sc;
  }
  __syncthreads();

  if (tid < 64) {
    float mx = -1e30f;
    #pragma unroll
    for (int j = 0; j < 10; ++j) mx = fmaxf(mx, ssm[tid][j]);
    float sum = 0.f;
    float e10[10];
    #pragma unroll
    for (int j = 0; j < 10; ++j) { e10[j] = __expf(ssm[tid][j] - mx); sum += e10[j]; }
    float inv = 1.0f / sum;
    #pragma unroll
    for (int j = 0; j < 10; ++j) ps[tid][j] = e10[j] * inv;
  }
  __syncthreads();

  for (int e = tid; e < 64 * 64; e += 256) {
    int tl = e >> 6, d = e & 63;
    float a = 0.f;
    #pragma unroll
    for (int j = 0; j < 10; ++j) a += ps[tl][j] * vs[tl + j][d];
    ctx[(size_t)(bb * T_ + t0 + tl) * D_ + hh * 64 + d] = f2bf(a);
  }
}

extern "C" void kernel_launch(void* const* d_in, const int* in_sizes, int n_in,
                              void* d_out, int out_size, void* d_ws, size_t ws_size,
                              hipStream_t stream) {
  const float* x     = (const float*)d_in[0];
  const float* gamma = (const float*)d_in[1];
  const float* beta  = (const float*)d_in[2];
  const float* Wq    = (const float*)d_in[3];
  const float* bq    = (const float*)d_in[4];
  const float* Wk    = (const float*)d_in[5];
  const float* bk    = (const float*)d_in[6];
  const float* Wv    = (const float*)d_in[7];
  const float* bv    = (const float*)d_in[8];
  const float* Wo    = (const float*)d_in[9];
  const float* bo    = (const float*)d_in[10];
  float* out = (float*)d_out;

  char* ws = (char*)d_ws;
  unsigned short* h   = (unsigned short*)(ws);                        // 4 MB
  unsigned short* Wt  = (unsigned short*)(ws + 4194304);              // 1.5 MB
  unsigned short* Wot = (unsigned short*)(ws + 5767168);              // 0.5 MB
  float* bias_cat     = (float*)(ws + 6291456);                       // 6 KB
  unsigned short* qkv = (unsigned short*)(ws + 6297600);              // 12 MB
  unsigned short* ctx = (unsigned short*)(ws + 6297600 + 12582912);   // 4 MB

  prep_kernel<<<257, 256, 0, stream>>>(Wq, Wk, Wv, Wo, bq, bk, bv, Wt, Wot, bias_cat);
  ln_kernel<<<1024, 256, 0, stream>>>(x, gamma, beta, h);
  gemm_bf16<1><<<dim3(12, 32), 256, 0, stream>>>(h, Wt, bias_cat, nullptr, qkv, NROW, NQKV, D_);
  attn_kernel<<<512, 256, 0, stream>>>(qkv, ctx);
  gemm_bf16<2><<<dim3(4, 32), 256, 0, stream>>>(ctx, Wot, bo, x, out, NROW, D_, D_);
}

// Round 15
// 123.908 us; speedup vs baseline: 1.1312x; 1.0487x over previous
//
#include <hip/hip_runtime.h>
#include <hip/hip_bf16.h>

#define B_ 2
#define T_ 2048
#define D_ 512
#define H_ 8
#define DH_ 64
#define NROW 4096
#define NQKV 1536

typedef __bf16 bf16x8 __attribute__((ext_vector_type(8)));
typedef float f32x4 __attribute__((ext_vector_type(4)));

__device__ __forceinline__ unsigned short f2bf(float f) {
  unsigned int u = __float_as_uint(f);
  unsigned int r = (u + 0x7fffu + ((u >> 16) & 1u)) >> 16;
  return (unsigned short)r;
}
__device__ __forceinline__ float bf2f(unsigned short s) {
  return __uint_as_float(((unsigned int)s) << 16);
}

__device__ __forceinline__ void gload_lds16(const void* g, void* l) {
  __builtin_amdgcn_global_load_lds(
      (__attribute__((address_space(1))) void*)(void*)(g),
      (__attribute__((address_space(3))) void*)(l), 16, 0, 0);
}

// ---- prep+ln fused (independent phases, block-range dispatch) ----
// blocks 0..255: 64x64 tile transposes f32->bf16 ({Wq,Wk,Wv}->Wt, Wo->Wot)
// block 256: bias concat
// blocks 257..1280: LayerNorm (4 rows/block)
__global__ __launch_bounds__(256) void prep_ln_kernel(
    const float* __restrict__ Wq, const float* __restrict__ Wk,
    const float* __restrict__ Wv, const float* __restrict__ Wo,
    const float* __restrict__ bq, const float* __restrict__ bk,
    const float* __restrict__ bv,
    const float* __restrict__ x, const float* __restrict__ gamma,
    const float* __restrict__ beta,
    unsigned short* __restrict__ Wt,   // [1536][512] bf16
    unsigned short* __restrict__ Wot,  // [512][512]  bf16
    float* __restrict__ bias_cat,      // [1536]
    unsigned short* __restrict__ h)    // [4096][512] bf16
{
  const int bid = blockIdx.x;
  const int tid = threadIdx.x;
  __shared__ unsigned short tile[64][66];

  if (bid < 256) {  // weight transpose
    const int mat = bid >> 6;
    const int tb = bid & 63;
    const int tn = tb >> 3, tk = tb & 7;
    const int k0 = tk << 6, n0 = tn << 6;
    const float* src = (mat == 0) ? Wq : (mat == 1) ? Wk : (mat == 2) ? Wv : Wo;
    unsigned short* dst = (mat < 3) ? (Wt + (size_t)mat * 512 * 512) : Wot;
    #pragma unroll
    for (int p = 0; p < 16; ++p) {
      int e = (p << 8) + tid;
      int kr = e >> 6, nc = e & 63;
      tile[kr][nc] = f2bf(src[(size_t)(k0 + kr) * 512 + n0 + nc]);
    }
    __syncthreads();
    #pragma unroll
    for (int p = 0; p < 16; ++p) {
      int e = (p << 8) + tid;
      int nr = e >> 6, kc = e & 63;
      dst[(size_t)(n0 + nr) * 512 + k0 + kc] = tile[kc][nr];
    }
    return;
  }
  if (bid == 256) {  // bias concat
    for (int i = tid; i < NQKV; i += 256) {
      const float* s = (i < 512) ? bq : ((i < 1024) ? bk : bv);
      bias_cat[i] = s[i & 511];
    }
    return;
  }
  // LayerNorm
  const int lane = tid & 63;
  const int row = ((bid - 257) << 2) + (tid >> 6);
  const float* xr = x + (size_t)row * D_ + lane * 8;
  float4 v0 = *(const float4*)xr;
  float4 v1 = *(const float4*)(xr + 4);
  float xv[8] = {v0.x, v0.y, v0.z, v0.w, v1.x, v1.y, v1.z, v1.w};
  float s = 0.f, ss = 0.f;
  #pragma unroll
  for (int i = 0; i < 8; ++i) { s += xv[i]; ss += xv[i] * xv[i]; }
  #pragma unroll
  for (int off = 32; off > 0; off >>= 1) {
    s  += __shfl_xor(s, off);
    ss += __shfl_xor(ss, off);
  }
  float mu  = s * (1.0f / D_);
  float var = ss * (1.0f / D_) - mu * mu;
  float rs  = rsqrtf(var + 1e-3f);
  const float* gp = gamma + lane * 8;
  const float* bp = beta + lane * 8;
  float4 g0 = *(const float4*)gp;
  float4 g1 = *(const float4*)(gp + 4);
  float4 b0 = *(const float4*)bp;
  float4 b1 = *(const float4*)(bp + 4);
  float gv[8] = {g0.x, g0.y, g0.z, g0.w, g1.x, g1.y, g1.z, g1.w};
  float bv8[8] = {b0.x, b0.y, b0.z, b0.w, b1.x, b1.y, b1.z, b1.w};
  unsigned int pk[4];
  #pragma unroll
  for (int i = 0; i < 4; ++i) {
    unsigned short lo = f2bf((xv[2*i]   - mu) * rs * gv[2*i]   + bv8[2*i]);
    unsigned short hi = f2bf((xv[2*i+1] - mu) * rs * gv[2*i+1] + bv8[2*i+1]);
    pk[i] = (unsigned int)lo | ((unsigned int)hi << 16);
  }
  uint4 out4 = make_uint4(pk[0], pk[1], pk[2], pk[3]);
  *(uint4*)(h + (size_t)row * D_ + lane * 8) = out4;
}

// ------- bf16 MFMA GEMM, tile 128 x BN: C[M][N] = A[M][K] * Bt[N][K]^T -------
// Double-buffered LDS, STAGE(t+1) before compute(t). 4 waves as 2x2.
// BN=128: wave tile 64x64 (acc 4x4). BN=64: wave tile 64x32 (acc 4x2).
// EPI=1: out bf16, += bias.  EPI=2: out f32, += bias + resid.
template<int EPI, int BN>
__global__ __launch_bounds__(256) void gemm_bf16(
    const unsigned short* __restrict__ A,
    const unsigned short* __restrict__ Bt,
    const float* __restrict__ bias,
    const float* __restrict__ resid,
    void* __restrict__ outp,
    int M, int N, int K)
{
  constexpr int NF = BN / 32;          // n-frags per wave
  constexpr int WAVE_N = BN / 2;       // cols per wave
  __shared__ unsigned short Asm[2][128 * 32];
  __shared__ unsigned short Bsm[2][BN * 32];
  const int tid = threadIdx.x;
  const int lane = tid & 63;
  const int w = tid >> 6;
  const int m0 = blockIdx.y << 7;
  const int n0 = blockIdx.x * BN;
  const int wr = w >> 1, wc = w & 1;

  f32x4 acc[4][NF];
  #pragma unroll
  for (int m = 0; m < 4; ++m)
    #pragma unroll
    for (int n = 0; n < NF; ++n) acc[m][n] = f32x4{0.f, 0.f, 0.f, 0.f};

  const int frow = lane & 15;
  const int fk = (lane >> 4) << 3;

  const int ca0 = (w << 7);            // A chunk bases (512 16B-chunks/tile)
  const int ca1 = ca0 + 64;
  const int c0 = ca0 + lane;
  const int c1 = ca1 + lane;
  const int cb0 = (w << 6) + lane;     // B chunk id for BN=64 (256 chunks)

  auto stage = [&](int k0, int buf) {
    gload_lds16(A + (size_t)(m0 + (c0 >> 2)) * K + k0 + ((c0 & 3) << 3),
                (char*)Asm[buf] + ca0 * 16);
    gload_lds16(A + (size_t)(m0 + (c1 >> 2)) * K + k0 + ((c1 & 3) << 3),
                (char*)Asm[buf] + ca1 * 16);
    if constexpr (BN == 128) {
      gload_lds16(Bt + (size_t)(n0 + (c0 >> 2)) * K + k0 + ((c0 & 3) << 3),
                  (char*)Bsm[buf] + ca0 * 16);
      gload_lds16(Bt + (size_t)(n0 + (c1 >> 2)) * K + k0 + ((c1 & 3) << 3),
                  (char*)Bsm[buf] + ca1 * 16);
    } else {
      gload_lds16(Bt + (size_t)(n0 + (cb0 >> 2)) * K + k0 + ((cb0 & 3) << 3),
                  (char*)Bsm[buf] + (w << 6) * 16);
    }
  };

  stage(0, 0);
  __syncthreads();

  const int NT = K >> 5;
  for (int t = 0; t < NT; ++t) {
    const int cur = t & 1;
    if (t + 1 < NT) stage((t + 1) << 5, cur ^ 1);
    bf16x8 a[4], b[NF];
    #pragma unroll
    for (int m = 0; m < 4; ++m)
      a[m] = *(const bf16x8*)&Asm[cur][((wr << 6) + (m << 4) + frow) * 32 + fk];
    #pragma unroll
    for (int n = 0; n < NF; ++n)
      b[n] = *(const bf16x8*)&Bsm[cur][(wc * WAVE_N + (n << 4) + frow) * 32 + fk];
    #pragma unroll
    for (int m = 0; m < 4; ++m)
      #pragma unroll
      for (int n = 0; n < NF; ++n)
        acc[m][n] = __builtin_amdgcn_mfma_f32_16x16x32_bf16(a[m], b[n], acc[m][n], 0, 0, 0);
    __syncthreads();
  }

  const int rbase = m0 + (wr << 6) + ((lane >> 4) << 2);
  const int cbase = n0 + wc * WAVE_N + (lane & 15);
  #pragma unroll
  for (int m = 0; m < 4; ++m) {
    #pragma unroll
    for (int n = 0; n < NF; ++n) {
      const int cc = cbase + (n << 4);
      const float bs = bias[cc];
      #pragma unroll
      for (int r = 0; r < 4; ++r) {
        const int rr = rbase + (m << 4) + r;
        const float val = acc[m][n][r] + bs;
        if (EPI == 1) {
          ((unsigned short*)outp)[(size_t)rr * N + cc] = f2bf(val);
        } else {
          const size_t o = (size_t)rr * N + cc;
          ((float*)outp)[o] = val + resid[o];
        }
      }
    }
  }
}

// ---------------- windowed attention ----------------
// qs/ks padded to 65 floats/row (bank = (row+d)%32, conflict-free scores).
__global__ __launch_bounds__(256) void attn_kernel(
    const unsigned short* __restrict__ qkv,  // [4096][1536] bf16 (q|k|v)
    unsigned short* __restrict__ ctx)        // [4096][512] bf16
{
  __shared__ float qs[64][65];
  __shared__ float ks[80][65];
  __shared__ float vs[80][64];
  __shared__ float ssm[64][12];
  __shared__ float ps[64][12];
  const int tid = threadIdx.x;
  const int bx = blockIdx.x;
  const int chunk = bx & 31;
  const int hh = (bx >> 5) & 7;
  const int bb = bx >> 8;
  const int t0 = chunk << 6;
  const size_t base_bt = (size_t)(bb * T_) * NQKV + hh * 64;

  for (int e = tid; e < 64 * 64; e += 256) {
    int i = e >> 6, d = e & 63;
    qs[i][d] = bf2f(qkv[base_bt + (size_t)(t0 + i) * NQKV + d]);
  }
  for (int e = tid; e < 80 * 64; e += 256) {
    int i = e >> 6, d = e & 63;
    int tt = t0 - 6 + i;
    bool ok = (tt >= 0) && (tt < T_);
    if (ok) {
      size_t idx = base_bt + (size_t)tt * NQKV + d;
      ks[i][d] = bf2f(qkv[idx + 512]);
      vs[i][d] = bf2f(qkv[idx + 1024]);
    } else {
      ks[i][d] = 0.f;
      vs[i][d] = 0.f;
    }
  }
  __syncthreads();

  for (int e = tid; e < 640; e += 256) {
    int tl = e / 10, j = e - tl * 10;
    int tk = t0 + tl - 6 + j;
    float sc = -1e30f;
    if (tk >= 0 && tk < T_) {
      float a = 0.f;
      #pragma unroll
      for (int d = 0; d < 64; ++d) a += qs[tl][d] * ks[tl + j][d];
      sc = a * 0.125f;
    }
    ssm[tl][j] = sc;
  }
  __syncthreads();

  if (tid < 64) {
    float mx = -1e30f;
    #pragma unroll
    for (int j = 0; j < 10; ++j) mx = fmaxf(mx, ssm[tid][j]);
    float sum = 0.f;
    float e10[10];
    #pragma unroll
    for (int j = 0; j < 10; ++j) { e10[j] = __expf(ssm[tid][j] - mx); sum += e10[j]; }
    float inv = 1.0f / sum;
    #pragma unroll
    for (int j = 0; j < 10; ++j) ps[tid][j] = e10[j] * inv;
  }
  __syncthreads();

  for (int e = tid; e < 64 * 64; e += 256) {
    int tl = e >> 6, d = e & 63;
    float a = 0.f;
    #pragma unroll
    for (int j = 0; j < 10; ++j) a += ps[tl][j] * vs[tl + j][d];
    ctx[(size_t)(bb * T_ + t0 + tl) * D_ + hh * 64 + d] = f2bf(a);
  }
}

extern "C" void kernel_launch(void* const* d_in, const int* in_sizes, int n_in,
                              void* d_out, int out_size, void* d_ws, size_t ws_size,
                              hipStream_t stream) {
  const float* x     = (const float*)d_in[0];
  const float* gamma = (const float*)d_in[1];
  const float* beta  = (const float*)d_in[2];
  const float* Wq    = (const float*)d_in[3];
  const float* bq    = (const float*)d_in[4];
  const float* Wk    = (const float*)d_in[5];
  const float* bk    = (const float*)d_in[6];
  const float* Wv    = (const float*)d_in[7];
  const float* bv    = (const float*)d_in[8];
  const float* Wo    = (const float*)d_in[9];
  const float* bo    = (const float*)d_in[10];
  float* out = (float*)d_out;

  char* ws = (char*)d_ws;
  unsigned short* h   = (unsigned short*)(ws);                        // 4 MB
  unsigned short* Wt  = (unsigned short*)(ws + 4194304);              // 1.5 MB
  unsigned short* Wot = (unsigned short*)(ws + 5767168);              // 0.5 MB
  float* bias_cat     = (float*)(ws + 6291456);                       // 6 KB
  unsigned short* qkv = (unsigned short*)(ws + 6297600);              // 12 MB
  unsigned short* ctx = (unsigned short*)(ws + 6297600 + 12582912);   // 4 MB

  prep_ln_kernel<<<1281, 256, 0, stream>>>(Wq, Wk, Wv, Wo, bq, bk, bv,
                                           x, gamma, beta, Wt, Wot, bias_cat, h);
  gemm_bf16<1, 64><<<dim3(24, 32), 256, 0, stream>>>(h, Wt, bias_cat, nullptr, qkv, NROW, NQKV, D_);
  attn_kernel<<<512, 256, 0, stream>>>(qkv, ctx);
  gemm_bf16<2, 64><<<dim3(8, 32), 256, 0, stream>>>(ctx, Wot, bo, x, out, NROW, D_, D_);
}

// Round 17
// 116.814 us; speedup vs baseline: 1.1999x; 1.0607x over previous
//
#include <hip/hip_runtime.h>
#include <hip/hip_bf16.h>

#define B_ 2
#define T_ 2048
#define D_ 512
#define H_ 8
#define DH_ 64
#define NROW 4096
#define NQKV 1536

typedef __bf16 bf16x8 __attribute__((ext_vector_type(8)));
typedef float f32x4 __attribute__((ext_vector_type(4)));

__device__ __forceinline__ unsigned short f2bf(float f) {
  unsigned int u = __float_as_uint(f);
  unsigned int r = (u + 0x7fffu + ((u >> 16) & 1u)) >> 16;
  return (unsigned short)r;
}
__device__ __forceinline__ float bf2f(unsigned short s) {
  return __uint_as_float(((unsigned int)s) << 16);
}

__device__ __forceinline__ void gload_lds16(const void* g, void* l) {
  __builtin_amdgcn_global_load_lds(
      (__attribute__((address_space(1))) void*)(void*)(g),
      (__attribute__((address_space(3))) void*)(l), 16, 0, 0);
}

// ---- prep+ln fused (independent phases, block-range dispatch) ----
__global__ __launch_bounds__(256) void prep_ln_kernel(
    const float* __restrict__ Wq, const float* __restrict__ Wk,
    const float* __restrict__ Wv, const float* __restrict__ Wo,
    const float* __restrict__ bq, const float* __restrict__ bk,
    const float* __restrict__ bv,
    const float* __restrict__ x, const float* __restrict__ gamma,
    const float* __restrict__ beta,
    unsigned short* __restrict__ Wt,   // [1536][512] bf16
    unsigned short* __restrict__ Wot,  // [512][512]  bf16
    float* __restrict__ bias_cat,      // [1536]
    unsigned short* __restrict__ h)    // [4096][512] bf16
{
  const int bid = blockIdx.x;
  const int tid = threadIdx.x;
  __shared__ unsigned short tile[64][66];

  if (bid < 256) {  // weight transpose
    const int mat = bid >> 6;
    const int tb = bid & 63;
    const int tn = tb >> 3, tk = tb & 7;
    const int k0 = tk << 6, n0 = tn << 6;
    const float* src = (mat == 0) ? Wq : (mat == 1) ? Wk : (mat == 2) ? Wv : Wo;
    unsigned short* dst = (mat < 3) ? (Wt + (size_t)mat * 512 * 512) : Wot;
    #pragma unroll
    for (int p = 0; p < 16; ++p) {
      int e = (p << 8) + tid;
      int kr = e >> 6, nc = e & 63;
      tile[kr][nc] = f2bf(src[(size_t)(k0 + kr) * 512 + n0 + nc]);
    }
    __syncthreads();
    #pragma unroll
    for (int p = 0; p < 16; ++p) {
      int e = (p << 8) + tid;
      int nr = e >> 6, kc = e & 63;
      dst[(size_t)(n0 + nr) * 512 + k0 + kc] = tile[kc][nr];
    }
    return;
  }
  if (bid == 256) {  // bias concat
    for (int i = tid; i < NQKV; i += 256) {
      const float* s = (i < 512) ? bq : ((i < 1024) ? bk : bv);
      bias_cat[i] = s[i & 511];
    }
    return;
  }
  // LayerNorm
  const int lane = tid & 63;
  const int row = ((bid - 257) << 2) + (tid >> 6);
  const float* xr = x + (size_t)row * D_ + lane * 8;
  float4 v0 = *(const float4*)xr;
  float4 v1 = *(const float4*)(xr + 4);
  float xv[8] = {v0.x, v0.y, v0.z, v0.w, v1.x, v1.y, v1.z, v1.w};
  float s = 0.f, ss = 0.f;
  #pragma unroll
  for (int i = 0; i < 8; ++i) { s += xv[i]; ss += xv[i] * xv[i]; }
  #pragma unroll
  for (int off = 32; off > 0; off >>= 1) {
    s  += __shfl_xor(s, off);
    ss += __shfl_xor(ss, off);
  }
  float mu  = s * (1.0f / D_);
  float var = ss * (1.0f / D_) - mu * mu;
  float rs  = rsqrtf(var + 1e-3f);
  const float* gp = gamma + lane * 8;
  const float* bp = beta + lane * 8;
  float4 g0 = *(const float4*)gp;
  float4 g1 = *(const float4*)(gp + 4);
  float4 b0 = *(const float4*)bp;
  float4 b1 = *(const float4*)(bp + 4);
  float gv[8] = {g0.x, g0.y, g0.z, g0.w, g1.x, g1.y, g1.z, g1.w};
  float bv8[8] = {b0.x, b0.y, b0.z, b0.w, b1.x, b1.y, b1.z, b1.w};
  unsigned int pk[4];
  #pragma unroll
  for (int i = 0; i < 4; ++i) {
    unsigned short lo = f2bf((xv[2*i]   - mu) * rs * gv[2*i]   + bv8[2*i]);
    unsigned short hi = f2bf((xv[2*i+1] - mu) * rs * gv[2*i+1] + bv8[2*i+1]);
    pk[i] = (unsigned int)lo | ((unsigned int)hi << 16);
  }
  uint4 out4 = make_uint4(pk[0], pk[1], pk[2], pk[3]);
  *(uint4*)(h + (size_t)row * D_ + lane * 8) = out4;
}

// ------- bf16 MFMA GEMM, tile 128x64, BK=64: C = A[M][K] * Bt[N][K]^T -------
// Double-buffered, prefetch-before-compute, 8 K-steps (half the barriers of
// BK=32). LDS XOR-swizzle per rule 21: linear gload_lds dest + inverse-
// swizzled SOURCE chunk (g = (S&7)^(r&7)) + swizzled READ slot -> fragment
// ds_read_b128 goes 16-way -> 2-way (free). 48 KB LDS, 3 blocks/CU.
// EPI=1: out bf16, += bias.  EPI=2: out f32, += bias + resid.
template<int EPI>
__global__ __launch_bounds__(256) void gemm_bf16(
    const unsigned short* __restrict__ A,
    const unsigned short* __restrict__ Bt,
    const float* __restrict__ bias,
    const float* __restrict__ resid,
    void* __restrict__ outp,
    int M, int N, int K)
{
  __shared__ unsigned short Asm[2][128 * 64];
  __shared__ unsigned short Bsm[2][64 * 64];
  const int tid = threadIdx.x;
  const int lane = tid & 63;
  const int w = tid >> 6;
  const int m0 = blockIdx.y << 7;
  const int n0 = blockIdx.x << 6;
  const int wr = w >> 1, wc = w & 1;

  f32x4 acc[4][2];
  #pragma unroll
  for (int m = 0; m < 4; ++m)
    #pragma unroll
    for (int n = 0; n < 2; ++n) acc[m][n] = f32x4{0.f, 0.f, 0.f, 0.f};

  const int frow = lane & 15;
  const int fsl = lane >> 4;           // 16B-slot sub-index from fk

  auto stage = [&](int k0, int buf) {
    #pragma unroll
    for (int q = 0; q < 4; ++q) {      // A: 1024 chunks (128 rows x 8)
      const int S = (w << 8) + (q << 6) + lane;
      const int r = S >> 3, g = (S & 7) ^ (r & 7);
      gload_lds16(A + (size_t)(m0 + r) * K + k0 + (g << 3),
                  (char*)Asm[buf] + (((w << 8) + (q << 6)) << 4));
    }
    #pragma unroll
    for (int q = 0; q < 2; ++q) {      // B: 512 chunks (64 rows x 8)
      const int S = (w << 7) + (q << 6) + lane;
      const int r = S >> 3, g = (S & 7) ^ (r & 7);
      gload_lds16(Bt + (size_t)(n0 + r) * K + k0 + (g << 3),
                  (char*)Bsm[buf] + (((w << 7) + (q << 6)) << 4));
    }
  };

  stage(0, 0);
  __syncthreads();

  const int NT = K >> 6;
  for (int t = 0; t < NT; ++t) {
    const int cur = t & 1;
    if (t + 1 < NT) stage((t + 1) << 6, cur ^ 1);
    bf16x8 a[4][2], b[2][2];
    #pragma unroll
    for (int m = 0; m < 4; ++m) {
      const int r = (wr << 6) + (m << 4) + frow;
      #pragma unroll
      for (int kk = 0; kk < 2; ++kk) {
        const int slot = ((kk << 2) + fsl) ^ (r & 7);
        a[m][kk] = *(const bf16x8*)((char*)Asm[cur] + (r << 7) + (slot << 4));
      }
    }
    #pragma unroll
    for (int n = 0; n < 2; ++n) {
      const int r = (wc << 5) + (n << 4) + frow;
      #pragma unroll
      for (int kk = 0; kk < 2; ++kk) {
        const int slot = ((kk << 2) + fsl) ^ (r & 7);
        b[n][kk] = *(const bf16x8*)((char*)Bsm[cur] + (r << 7) + (slot << 4));
      }
    }
    #pragma unroll
    for (int m = 0; m < 4; ++m)
      #pragma unroll
      for (int n = 0; n < 2; ++n)
        #pragma unroll
        for (int kk = 0; kk < 2; ++kk)
          acc[m][n] = __builtin_amdgcn_mfma_f32_16x16x32_bf16(a[m][kk], b[n][kk], acc[m][n], 0, 0, 0);
    __syncthreads();
  }

  const int rbase = m0 + (wr << 6) + ((lane >> 4) << 2);
  const int cbase = n0 + (wc << 5) + (lane & 15);
  #pragma unroll
  for (int m = 0; m < 4; ++m) {
    #pragma unroll
    for (int n = 0; n < 2; ++n) {
      const int cc = cbase + (n << 4);
      const float bs = bias[cc];
      #pragma unroll
      for (int r = 0; r < 4; ++r) {
        const int rr = rbase + (m << 4) + r;
        const float val = acc[m][n][r] + bs;
        if (EPI == 1) {
          ((unsigned short*)outp)[(size_t)rr * N + cc] = f2bf(val);
        } else {
          const size_t o = (size_t)rr * N + cc;
          ((float*)outp)[o] = val + resid[o];
        }
      }
    }
  }
}

// ---------------- windowed attention ----------------
// qs/ks padded to 65 (conflict-free scores); staging vectorized uint4=8 bf16.
__global__ __launch_bounds__(256) void attn_kernel(
    const unsigned short* __restrict__ qkv,  // [4096][1536] bf16 (q|k|v)
    unsigned short* __restrict__ ctx)        // [4096][512] bf16
{
  __shared__ float qs[64][65];
  __shared__ float ks[80][65];
  __shared__ float vs[80][64];
  __shared__ float ssm[64][13];
  __shared__ float ps[64][13];
  const int tid = threadIdx.x;
  const int bx = blockIdx.x;
  const int chunk = bx & 31;
  const int hh = (bx >> 5) & 7;
  const int bb = bx >> 8;
  const int t0 = chunk << 6;
  const size_t base_bt = (size_t)(bb * T_) * NQKV + hh * 64;

  for (int c = tid; c < 512; c += 256) {       // q: 64 rows x 8 groups
    int row = c >> 3, grp = c & 7;
    uint4 u = *(const uint4*)(qkv + base_bt + (size_t)(t0 + row) * NQKV + (grp << 3));
    float* q8 = &qs[row][grp << 3];
    unsigned int uu[4] = {u.x, u.y, u.z, u.w};
    #pragma unroll
    for (int i = 0; i < 4; ++i) {
      q8[2*i]   = bf2f((unsigned short)(uu[i] & 0xffff));
      q8[2*i+1] = bf2f((unsigned short)(uu[i] >> 16));
    }
  }
  for (int c = tid; c < 1280; c += 256) {      // k then v: 80 rows x 8 groups
    int kc = (c < 640) ? c : (c - 640);
    int row = kc >> 3, grp = kc & 7;
    int tt = t0 - 6 + row;
    float* d8 = (c < 640) ? &ks[row][grp << 3] : &vs[row][grp << 3];
    if (tt >= 0 && tt < T_) {
      size_t idx = base_bt + (size_t)tt * NQKV + (grp << 3) + ((c < 640) ? 512 : 1024);
      uint4 u = *(const uint4*)(qkv + idx);
      unsigned int uu[4] = {u.x, u.y, u.z, u.w};
      #pragma unroll
      for (int i = 0; i < 4; ++i) {
        d8[2*i]   = bf2f((unsigned short)(uu[i] & 0xffff));
        d8[2*i+1] = bf2f((unsigned short)(uu[i] >> 16));
      }
    } else {
      #pragma unroll
      for (int i = 0; i < 8; ++i) d8[i] = 0.f;
    }
  }
  __syncthreads();

  for (int e = tid; e < 640; e += 256) {
    int tl = e / 10, j = e - tl * 10;
    int tk = t0 + tl - 6 + j;
    float sc = -1e30f;
    if (tk >= 0 && tk < T_) {
      float a = 0.f;
      #pragma unroll
      for (int d = 0; d < 64; ++d) a += qs[tl][d] * ks[tl + j][d];
      sc = a * 0.125f;
    }
    ssm[tl][j] = sc;
  }
  __syncthreads();

  if (tid < 64) {
    float mx = -1e30f;
    #pragma unroll
    for (int j = 0; j < 10; ++j) mx = fmaxf(mx, ssm[tid][j]);
    float sum = 0.f;
    float e10[10];
    #pragma unroll
    for (int j = 0; j < 10; ++j) { e10[j] = __expf(ssm[tid][j] - mx); sum += e10[j]; }
    float inv = 1.0f / sum;
    #pragma unroll
    for (int j = 0; j < 10; ++j) ps[tid][j] = e10[j] * inv;
  }
  __syncthreads();

  for (int e = tid; e < 64 * 64; e += 256) {
    int tl = e >> 6, d = e & 63;
    float a = 0.f;
    #pragma unroll
    for (int j = 0; j < 10; ++j) a += ps[tl][j] * vs[tl + j][d];
    ctx[(size_t)(bb * T_ + t0 + tl) * D_ + hh * 64 + d] = f2bf(a);
  }
}

extern "C" void kernel_launch(void* const* d_in, const int* in_sizes, int n_in,
                              void* d_out, int out_size, void* d_ws, size_t ws_size,
                              hipStream_t stream) {
  const float* x     = (const float*)d_in[0];
  const float* gamma = (const float*)d_in[1];
  const float* beta  = (const float*)d_in[2];
  const float* Wq    = (const float*)d_in[3];
  const float* bq    = (const float*)d_in[4];
  const float* Wk    = (const float*)d_in[5];
  const float* bk    = (const float*)d_in[6];
  const float* Wv    = (const float*)d_in[7];
  const float* bv    = (const float*)d_in[8];
  const float* Wo    = (const float*)d_in[9];
  const float* bo    = (const float*)d_in[10];
  float* out = (float*)d_out;

  char* ws = (char*)d_ws;
  unsigned short* h   = (unsigned short*)(ws);                        // 4 MB
  unsigned short* Wt  = (unsigned short*)(ws + 4194304);              // 1.5 MB
  unsigned short* Wot = (unsigned short*)(ws + 5767168);              // 0.5 MB
  float* bias_cat     = (float*)(ws + 6291456);                       // 6 KB
  unsigned short* qkv = (unsigned short*)(ws + 6297600);              // 12 MB
  unsigned short* ctx = (unsigned short*)(ws + 6297600 + 12582912);   // 4 MB

  prep_ln_kernel<<<1281, 256, 0, stream>>>(Wq, Wk, Wv, Wo, bq, bk, bv,
                                           x, gamma, beta, Wt, Wot, bias_cat, h);
  gemm_bf16<1><<<dim3(24, 32), 256, 0, stream>>>(h, Wt, bias_cat, nullptr, qkv, NROW, NQKV, D_);
  attn_kernel<<<512, 256, 0, stream>>>(qkv, ctx);
  gemm_bf16<2><<<dim3(8, 32), 256, 0, stream>>>(ctx, Wot, bo, x, out, NROW, D_, D_);
}